// Round 1
// baseline (1215.506 us; speedup 1.0000x reference)
//
#include <hip/hip_runtime.h>
#include <hip/hip_bf16.h>
#include <stdint.h>

// ---------------------------------------------------------------------------
// GraphAttentionLayer: out = softmax(lrelu(s1[i]+s2[j])) @ h,  h = x @ W^T
// Strategy: bf16 MFMA for both big GEMMs; rank-1 logits => no QK^T GEMM,
// row max m_i = lrelu(s1_i + max(s2)) in closed form (lrelu monotone).
// ---------------------------------------------------------------------------

typedef float  f32x4  __attribute__((ext_vector_type(4)));
typedef __bf16 bf16x8 __attribute__((ext_vector_type(8)));

#define AS1 __attribute__((address_space(1)))
#define AS3 __attribute__((address_space(3)))

__device__ __forceinline__ uint16_t f2bf_u(float f) {   // RNE fp32 -> bf16 bits
  union { float f; uint32_t u; } x; x.f = f;
  return (uint16_t)((x.u + 0x7FFFu + ((x.u >> 16) & 1u)) >> 16);
}
__device__ __forceinline__ float bfu2f(uint16_t v) {
  union { uint32_t u; float f; } x; x.u = ((uint32_t)v) << 16;
  return x.f;
}

// --------------------------- fp32 -> bf16 convert ---------------------------
__global__ __launch_bounds__(256) void cvt_f32_to_bf16(
    const float* __restrict__ in, uint16_t* __restrict__ out, int n4) {
  int idx = blockIdx.x * 256 + threadIdx.x;
  int stride = gridDim.x * 256;
  for (int i = idx; i < n4; i += stride) {
    float4 v = ((const float4*)in)[i];
    ushort4 o;
    o.x = f2bf_u(v.x); o.y = f2bf_u(v.y); o.z = f2bf_u(v.z); o.w = f2bf_u(v.w);
    ((ushort4*)out)[i] = o;
  }
}

// --------------------------- NT bf16 GEMM (m97-style) -----------------------
// C[M][N] = sum_k A[M][K] * B[N][K].  128x128 tile, BK=32, 4 waves (2x2 of
// 64x64), 16x16x32 bf16 MFMA, global_load_lds width=16 staging.
template<bool OUT_BF16, bool SCALE>
__global__ __launch_bounds__(256, 2) void gemm_nt(
    const uint16_t* __restrict__ A, const uint16_t* __restrict__ B,
    void* __restrict__ C, const float* __restrict__ rowScale,
    int M, int N, int K) {
  __shared__ alignas(16) uint16_t As[128 * 32];
  __shared__ alignas(16) uint16_t Bs[128 * 32];

  const int tid  = threadIdx.x;
  const int wave = tid >> 6;
  const int lane = tid & 63;
  const int mBase = blockIdx.y * 128;
  const int nBase = blockIdx.x * 128;

  // Staging: tile is 128x32 bf16 = 8192B = 512 chunks of 16B.
  // Round r: chunk c = r*256 + wave*64 + lane  ->  LDS byte c*16 (= wave-
  // uniform base + lane*16, as global_load_lds requires), tile row c>>2,
  // col elems (c&3)*8.
  const int c0  = wave * 64 + lane;
  const int ar0 = c0 >> 2;
  const int ac0 = (c0 & 3) * 8;
  const uint16_t* Ag0 = A + (size_t)(mBase + ar0)      * K + ac0;
  const uint16_t* Ag1 = A + (size_t)(mBase + 64 + ar0) * K + ac0;
  const uint16_t* Bg0 = B + (size_t)(nBase + ar0)      * K + ac0;
  const uint16_t* Bg1 = B + (size_t)(nBase + 64 + ar0) * K + ac0;
  uint16_t* AsW0 = As + wave * 512;          // byte off: wave*1024
  uint16_t* AsW1 = As + 2048 + wave * 512;   // byte off: 4096 + wave*1024
  uint16_t* BsW0 = Bs + wave * 512;
  uint16_t* BsW1 = Bs + 2048 + wave * 512;

  const int wm = (wave & 1) * 64;   // wave's 64x64 quadrant
  const int wn = (wave >> 1) * 64;
  const int lr = lane & 15;         // m (or n) within 16x16 fragment
  const int lk = (lane >> 4) * 8;   // k offset within fragment

  f32x4 acc[4][4];
#pragma unroll
  for (int mi = 0; mi < 4; mi++)
#pragma unroll
    for (int ni = 0; ni < 4; ni++) acc[mi][ni] = (f32x4){0.f, 0.f, 0.f, 0.f};

  for (int k0 = 0; k0 < K; k0 += 32) {
    __builtin_amdgcn_global_load_lds((const AS1 void*)(Ag0 + k0), (AS3 void*)AsW0, 16, 0, 0);
    __builtin_amdgcn_global_load_lds((const AS1 void*)(Ag1 + k0), (AS3 void*)AsW1, 16, 0, 0);
    __builtin_amdgcn_global_load_lds((const AS1 void*)(Bg0 + k0), (AS3 void*)BsW0, 16, 0, 0);
    __builtin_amdgcn_global_load_lds((const AS1 void*)(Bg1 + k0), (AS3 void*)BsW1, 16, 0, 0);
    __syncthreads();

    bf16x8 af[4], bfr[4];
#pragma unroll
    for (int mi = 0; mi < 4; mi++)
      af[mi] = *(const bf16x8*)(As + (wm + mi * 16 + lr) * 32 + lk);
#pragma unroll
    for (int ni = 0; ni < 4; ni++)
      bfr[ni] = *(const bf16x8*)(Bs + (wn + ni * 16 + lr) * 32 + lk);
#pragma unroll
    for (int mi = 0; mi < 4; mi++)
#pragma unroll
      for (int ni = 0; ni < 4; ni++)
        acc[mi][ni] = __builtin_amdgcn_mfma_f32_16x16x32_bf16(
            af[mi], bfr[ni], acc[mi][ni], 0, 0, 0);
    __syncthreads();
  }

  // Epilogue. C/D layout: row = (lane>>4)*4 + r, col = lane&15.
  const int row0 = mBase + wm + (lane >> 4) * 4;
  const int col0 = nBase + wn + lr;
#pragma unroll
  for (int mi = 0; mi < 4; mi++) {
#pragma unroll
    for (int r = 0; r < 4; r++) {
      const int row = row0 + mi * 16 + r;
      float scale = 1.0f;
      if (SCALE) scale = rowScale[row];
#pragma unroll
      for (int ni = 0; ni < 4; ni++) {
        const int col = col0 + ni * 16;
        float v = acc[mi][ni][r];
        if (SCALE) v *= scale;
        if (OUT_BF16)
          ((uint16_t*)C)[(size_t)row * N + col] = f2bf_u(v);
        else
          ((float*)C)[(size_t)row * N + col] = v;
      }
    }
  }
}

// --------------------------- s1/s2 GEMV (split-K + atomics) -----------------
__global__ __launch_bounds__(256) void zero_s(float* s1, float* s2) {
  int t = blockIdx.x * 256 + threadIdx.x;
  if (t < 8192) { s1[t] = 0.f; s2[t] = 0.f; }
}

// s1[i] = sum_k hT[k][i]*a[k];  s2[i] = sum_k hT[k][i]*a[4096+k]
// grid (16 i-chunks of 512 cols, 16 k-chunks of 256 rows)
__global__ __launch_bounds__(256) void s_kernel(
    const uint16_t* __restrict__ hT, const float* __restrict__ a,
    float* __restrict__ s1, float* __restrict__ s2) {
  const int t = threadIdx.x;
  const int i = blockIdx.x * 512 + t * 2;
  const int k0 = blockIdx.y * 256;
  float a1l = 0.f, a1h = 0.f, a2l = 0.f, a2h = 0.f;
  for (int kk = 0; kk < 256; kk++) {
    const int k = k0 + kk;
    uint32_t w = *(const uint32_t*)(hT + (size_t)k * 8192 + i);
    float lo = bfu2f((uint16_t)w), hi = bfu2f((uint16_t)(w >> 16));
    float a1k = a[k], a2k = a[4096 + k];
    a1l += a1k * lo; a1h += a1k * hi;
    a2l += a2k * lo; a2h += a2k * hi;
  }
  atomicAdd(&s1[i], a1l); atomicAdd(&s1[i + 1], a1h);
  atomicAdd(&s2[i], a2l); atomicAdd(&s2[i + 1], a2h);
}

__global__ __launch_bounds__(256) void max_kernel(
    const float* __restrict__ s2, float* __restrict__ out) {
  float m = -1e30f;
  for (int k = threadIdx.x; k < 8192; k += 256) m = fmaxf(m, s2[k]);
  for (int off = 32; off > 0; off >>= 1) m = fmaxf(m, __shfl_down(m, off, 64));
  __shared__ float red[4];
  if ((threadIdx.x & 63) == 0) red[threadIdx.x >> 6] = m;
  __syncthreads();
  if (threadIdx.x == 0) out[0] = fmaxf(fmaxf(red[0], red[1]), fmaxf(red[2], red[3]));
}

// --------------------------- P = exp(lrelu(s1+s2)-m) bf16, rcp_l ------------
__global__ __launch_bounds__(256) void p_kernel(
    const float* __restrict__ s1, const float* __restrict__ s2,
    const float* __restrict__ s2max, uint16_t* __restrict__ P,
    float* __restrict__ rcp_l) {
  const int i = blockIdx.x;
  const int t = threadIdx.x;
  const float s1i = s1[i];
  float mz = s1i + s2max[0];
  const float mi = mz > 0.f ? mz : 0.2f * mz;   // exact row max (lrelu monotone)
  float lsum = 0.f;
  uint16_t* Prow = P + (size_t)i * 8192;
  for (int jj = 0; jj < 16; jj++) {
    const int j = (jj * 256 + t) * 2;
    float2 sv = *(const float2*)(s2 + j);
    float e0 = s1i + sv.x; e0 = e0 > 0.f ? e0 : 0.2f * e0;
    float e1 = s1i + sv.y; e1 = e1 > 0.f ? e1 : 0.2f * e1;
    float p0 = __expf(e0 - mi);
    float p1 = __expf(e1 - mi);
    lsum += p0 + p1;
    uint32_t pk = (uint32_t)f2bf_u(p0) | ((uint32_t)f2bf_u(p1) << 16);
    *(uint32_t*)(Prow + j) = pk;
  }
  for (int off = 32; off > 0; off >>= 1) lsum += __shfl_down(lsum, off, 64);
  __shared__ float red[4];
  if ((t & 63) == 0) red[t >> 6] = lsum;
  __syncthreads();
  if (t == 0) rcp_l[i] = 1.0f / (red[0] + red[1] + red[2] + red[3]);
}

// ---------------------------------------------------------------------------
extern "C" void kernel_launch(void* const* d_in, const int* in_sizes, int n_in,
                              void* d_out, int out_size, void* d_ws, size_t ws_size,
                              hipStream_t stream) {
  const float* x = (const float*)d_in[0];   // [8192][4096] fp32
  const float* W = (const float*)d_in[1];   // [4096][4096] fp32
  const float* a = (const float*)d_in[2];   // [8192] fp32
  float* out = (float*)d_out;               // [8192][4096] fp32

  char* ws = (char*)d_ws;
  // layout: hT(64MB) | s1,s2,rcp_l,s2max | regionB: P(128MB) overlapping
  // x_bf16(64MB)+W_bf16(32MB) (x/W dead before P is written)
  uint16_t* hT    = (uint16_t*)ws;                       // 4096*8192*2 = 67108864
  float*    s1    = (float*)(ws + 67108864);             // 32KB
  float*    s2    = (float*)(ws + 67141632);             // 32KB
  float*    rcp_l = (float*)(ws + 67174400);             // 32KB
  float*    s2max = (float*)(ws + 67207168);             // 4B (padded)
  char*     rB    = ws + 67208192;                       // 1KB-aligned
  uint16_t* Pm    = (uint16_t*)rB;                       // 8192*8192*2 = 134217728
  uint16_t* xb    = (uint16_t*)rB;                       // overlaps Pm
  uint16_t* Wb    = (uint16_t*)(rB + 67108864);          // 4096*4096*2
  // total ws use: 67208192 + 134217728 = 201425920 bytes

  cvt_f32_to_bf16<<<1024, 256, 0, stream>>>(x, xb, (8192 * 4096) / 4);
  cvt_f32_to_bf16<<<1024, 256, 0, stream>>>(W, Wb, (4096 * 4096) / 4);

  // GEMM1: hT[o][i] = sum_k W[o][k] x[i][k]   (M=4096, N=8192, K=4096)
  gemm_nt<true, false><<<dim3(64, 32), 256, 0, stream>>>(
      Wb, xb, hT, nullptr, 4096, 8192, 4096);

  zero_s<<<32, 256, 0, stream>>>(s1, s2);
  s_kernel<<<dim3(16, 16), 256, 0, stream>>>(hT, a, s1, s2);
  max_kernel<<<1, 256, 0, stream>>>(s2, s2max);
  p_kernel<<<8192, 256, 0, stream>>>(s1, s2, s2max, Pm, rcp_l);

  // GEMM2: out[i][n] = (sum_j P[i][j] hT[n][j]) * rcp_l[i]
  //        (M=8192, N=4096, K=8192)
  gemm_nt<false, true><<<dim3(32, 64), 256, 0, stream>>>(
      Pm, hT, out, rcp_l, 8192, 4096, 8192);
}

// Round 2
// 1013.112 us; speedup vs baseline: 1.1998x; 1.1998x over previous
//
#include <hip/hip_runtime.h>
#include <hip/hip_bf16.h>
#include <stdint.h>

// ---------------------------------------------------------------------------
// GraphAttentionLayer: out = softmax(lrelu(s1_i + s2_j)) @ h,  h = x @ W^T
// Round 2: eliminate the attention@h GEMM entirely.
//   exp(lrelu(t)) = exp(0.2t) + 1[t>0](exp(t)-exp(0.2t)), t = s1_i+s2_j,
//   and both pieces factorize; active set {j: s2_j > -s1_i} is a PREFIX of
//   j sorted by s2 descending. So out rows are linear combos of prefix-sum
//   rows of weighted h: numer = q1*(A - B(c_i)) + q2*C(c_i).
// ---------------------------------------------------------------------------

typedef float  f32x4  __attribute__((ext_vector_type(4)));
typedef __bf16 bf16x8 __attribute__((ext_vector_type(8)));

#define AS1 __attribute__((address_space(1)))
#define AS3 __attribute__((address_space(3)))

constexpr int NB = 8192;            // batch rows (i and j)
constexpr int DF = 4096;            // features n (= D_OUT) ; also K of GEMM1
constexpr int CHUNK = 256;          // cumsum chunk length (c-dimension split)
constexpr int NCHUNK = NB / CHUNK;  // 32

__device__ __forceinline__ uint16_t f2bf_u(float f) {   // RNE fp32 -> bf16
  union { float f; uint32_t u; } x; x.f = f;
  return (uint16_t)((x.u + 0x7FFFu + ((x.u >> 16) & 1u)) >> 16);
}
__device__ __forceinline__ float bfu2f(uint16_t v) {
  union { uint32_t u; float f; } x; x.u = ((uint32_t)v) << 16;
  return x.f;
}

// --------------------------- fp32 -> bf16 convert ---------------------------
__global__ __launch_bounds__(256) void cvt_f32_to_bf16(
    const float* __restrict__ in, uint16_t* __restrict__ out, int n4) {
  int idx = blockIdx.x * 256 + threadIdx.x;
  int stride = gridDim.x * 256;
  for (int i = idx; i < n4; i += stride) {
    float4 v = ((const float4*)in)[i];
    ushort4 o;
    o.x = f2bf_u(v.x); o.y = f2bf_u(v.y); o.z = f2bf_u(v.z); o.w = f2bf_u(v.w);
    ((ushort4*)out)[i] = o;
  }
}

// --------------------------- NT bf16 GEMM (m97-style, unchanged) ------------
template<bool OUT_BF16>
__global__ __launch_bounds__(256, 2) void gemm_nt(
    const uint16_t* __restrict__ A, const uint16_t* __restrict__ B,
    void* __restrict__ C, int M, int N, int K) {
  __shared__ alignas(16) uint16_t As[128 * 32];
  __shared__ alignas(16) uint16_t Bs[128 * 32];

  const int tid  = threadIdx.x;
  const int wave = tid >> 6;
  const int lane = tid & 63;
  const int mBase = blockIdx.y * 128;
  const int nBase = blockIdx.x * 128;

  const int c0  = wave * 64 + lane;
  const int ar0 = c0 >> 2;
  const int ac0 = (c0 & 3) * 8;
  const uint16_t* Ag0 = A + (size_t)(mBase + ar0)      * K + ac0;
  const uint16_t* Ag1 = A + (size_t)(mBase + 64 + ar0) * K + ac0;
  const uint16_t* Bg0 = B + (size_t)(nBase + ar0)      * K + ac0;
  const uint16_t* Bg1 = B + (size_t)(nBase + 64 + ar0) * K + ac0;
  uint16_t* AsW0 = As + wave * 512;
  uint16_t* AsW1 = As + 2048 + wave * 512;
  uint16_t* BsW0 = Bs + wave * 512;
  uint16_t* BsW1 = Bs + 2048 + wave * 512;

  const int wm = (wave & 1) * 64;
  const int wn = (wave >> 1) * 64;
  const int lr = lane & 15;
  const int lk = (lane >> 4) * 8;

  f32x4 acc[4][4];
#pragma unroll
  for (int mi = 0; mi < 4; mi++)
#pragma unroll
    for (int ni = 0; ni < 4; ni++) acc[mi][ni] = (f32x4){0.f, 0.f, 0.f, 0.f};

  for (int k0 = 0; k0 < K; k0 += 32) {
    __builtin_amdgcn_global_load_lds((const AS1 void*)(Ag0 + k0), (AS3 void*)AsW0, 16, 0, 0);
    __builtin_amdgcn_global_load_lds((const AS1 void*)(Ag1 + k0), (AS3 void*)AsW1, 16, 0, 0);
    __builtin_amdgcn_global_load_lds((const AS1 void*)(Bg0 + k0), (AS3 void*)BsW0, 16, 0, 0);
    __builtin_amdgcn_global_load_lds((const AS1 void*)(Bg1 + k0), (AS3 void*)BsW1, 16, 0, 0);
    __syncthreads();

    bf16x8 af[4], bfr[4];
#pragma unroll
    for (int mi = 0; mi < 4; mi++)
      af[mi] = *(const bf16x8*)(As + (wm + mi * 16 + lr) * 32 + lk);
#pragma unroll
    for (int ni = 0; ni < 4; ni++)
      bfr[ni] = *(const bf16x8*)(Bs + (wn + ni * 16 + lr) * 32 + lk);
#pragma unroll
    for (int mi = 0; mi < 4; mi++)
#pragma unroll
      for (int ni = 0; ni < 4; ni++)
        acc[mi][ni] = __builtin_amdgcn_mfma_f32_16x16x32_bf16(
            af[mi], bfr[ni], acc[mi][ni], 0, 0, 0);
    __syncthreads();
  }

  const int row0 = mBase + wm + (lane >> 4) * 4;
  const int col0 = nBase + wn + lr;
#pragma unroll
  for (int mi = 0; mi < 4; mi++) {
#pragma unroll
    for (int r = 0; r < 4; r++) {
      const int row = row0 + mi * 16 + r;
#pragma unroll
      for (int ni = 0; ni < 4; ni++) {
        const int col = col0 + ni * 16;
        float v = acc[mi][ni][r];
        if (OUT_BF16)
          ((uint16_t*)C)[(size_t)row * N + col] = f2bf_u(v);
        else
          ((float*)C)[(size_t)row * N + col] = v;
      }
    }
  }
}

// --------------------------- s1/s2: h @ a1, h @ a2 --------------------------
// one wave per row; h is [NB][DF] bf16 row-major
__global__ __launch_bounds__(256) void s12_kernel(
    const uint16_t* __restrict__ h, const float* __restrict__ a,
    float* __restrict__ s1, float* __restrict__ s2) {
  const int wave = threadIdx.x >> 6, lane = threadIdx.x & 63;
  const int row = blockIdx.x * 4 + wave;
  const uint32_t* hr = (const uint32_t*)(h + (size_t)row * DF);
  float d1 = 0.f, d2 = 0.f;
#pragma unroll 4
  for (int it = 0; it < DF / 128; it++) {   // 32 iters
    int u = it * 64 + lane;
    uint32_t hv = hr[u];
    float lo = bfu2f((uint16_t)hv), hi = bfu2f((uint16_t)(hv >> 16));
    int k = 2 * u;
    d1 += a[k] * lo + a[k + 1] * hi;
    d2 += a[DF + k] * lo + a[DF + k + 1] * hi;
  }
  for (int off = 32; off > 0; off >>= 1) {
    d1 += __shfl_down(d1, off, 64);
    d2 += __shfl_down(d2, off, 64);
  }
  if (lane == 0) { s1[row] = d1; s2[row] = d2; }
}

// --------------------------- rank sort of s2 (descending) -------------------
__global__ __launch_bounds__(256) void rank_kernel(
    const float* __restrict__ s2, int* __restrict__ pi,
    float* __restrict__ s2sorted) {
  __shared__ float ld[NB];   // 32 KB
  for (int idx = threadIdx.x; idx < NB; idx += 256) ld[idx] = s2[idx];
  __syncthreads();
  const int j = blockIdx.x * 256 + threadIdx.x;
  const float v = ld[j];
  int cnt = 0;
  for (int q = 0; q < NB / 4; q++) {
    float4 u = ((const float4*)ld)[q];
    int jj = q * 4;
    cnt += (u.x > v) || (u.x == v && (jj + 0) < j);
    cnt += (u.y > v) || (u.y == v && (jj + 1) < j);
    cnt += (u.z > v) || (u.z == v && (jj + 2) < j);
    cnt += (u.w > v) || (u.w == v && (jj + 3) < j);
  }
  pi[cnt] = j;
  s2sorted[cnt] = v;
}

// --------------------------- c_i = #{j : s2_j > -s1_i} ----------------------
__global__ __launch_bounds__(256) void count_kernel(
    const float* __restrict__ s1, const float* __restrict__ s2,
    int* __restrict__ ci) {
  __shared__ float ld[NB];
  for (int idx = threadIdx.x; idx < NB; idx += 256) ld[idx] = s2[idx];
  __syncthreads();
  const int i = blockIdx.x * 256 + threadIdx.x;
  const float thr = -s1[i];
  int cnt = 0;
  for (int q = 0; q < NB / 4; q++) {
    float4 u = ((const float4*)ld)[q];
    cnt += (u.x > thr) + (u.y > thr) + (u.z > thr) + (u.w > thr);
  }
  ci[i] = cnt;
}

// --------------------------- scalar weights + prefix sums -------------------
// wbg[c]=exp(0.2*s2sorted[c]), wcg[c]=exp(s2sorted[c]);
// Sb[c]/Sc[c] = inclusive prefix sums, Sb[0]=0, index c in [0,NB].
__global__ __launch_bounds__(256) void scan_kernel(
    const float* __restrict__ s2sorted, float* __restrict__ Sb,
    float* __restrict__ Sc, float* __restrict__ wbg, float* __restrict__ wcg) {
  __shared__ float pb[256], pc[256];
  const int t = threadIdx.x;
  float sb = 0.f, sc = 0.f;
  for (int c = t * 32; c < t * 32 + 32; c++) {
    float s = s2sorted[c];
    float wb = __expf(0.2f * s), wc = __expf(s);
    wbg[c] = wb; wcg[c] = wc;
    sb += wb; sc += wc;
  }
  pb[t] = sb; pc[t] = sc;
  __syncthreads();
  if (t == 0) {
    float rb = 0.f, rc = 0.f;
    for (int q = 0; q < 256; q++) {
      float tb = pb[q], tc = pc[q];
      pb[q] = rb; pc[q] = rc;
      rb += tb; rc += tc;
    }
    Sb[0] = 0.f; Sc[0] = 0.f;
    Sb[NB] = rb; Sc[NB] = rc;
  }
  __syncthreads();
  float rb = pb[t], rc = pc[t];
  for (int c = t * 32; c < t * 32 + 32; c++) {
    rb += wbg[c]; rc += wcg[c];
    Sb[c + 1] = rb; Sc[c + 1] = rc;
  }
}

// --------------------------- chunked weighted cumsums B, C ------------------
// Row r = k*CHUNK + c stores the WITHIN-CHUNK cumsum up to sorted pos r
// (inclusive). True prefix(cglob) = store[cglob-1] + off[chunk(cglob-1)].
template<bool F32>
__global__ __launch_bounds__(256) void cumsum_kernel(
    const uint16_t* __restrict__ h, const int* __restrict__ pi,
    const float* __restrict__ wbg, const float* __restrict__ wcg,
    void* __restrict__ Bst, void* __restrict__ Cst) {
  __shared__ int   pj[CHUNK];
  __shared__ float wb[CHUNK], wc[CHUNK];
  const int t = threadIdx.x;
  const int cb = blockIdx.x;       // column block (512 cols)
  const int k  = blockIdx.y;       // chunk
  if (t < CHUNK) {
    pj[t] = pi[k * CHUNK + t];
    wb[t] = wbg[k * CHUNK + t];
    wc[t] = wcg[k * CHUNK + t];
  }
  __syncthreads();
  const int n0 = cb * 512 + t * 2;
  float ab0 = 0.f, ab1 = 0.f, ac0 = 0.f, ac1 = 0.f;
#pragma unroll 4
  for (int c = 0; c < CHUNK; c++) {
    const int j = pj[c];
    uint32_t hv = *(const uint32_t*)(h + (size_t)j * DF + n0);
    float h0 = bfu2f((uint16_t)hv), h1 = bfu2f((uint16_t)(hv >> 16));
    float b = wb[c], cc = wc[c];
    ab0 += b * h0; ab1 += b * h1;
    ac0 += cc * h0; ac1 += cc * h1;
    size_t off = (size_t)(k * CHUNK + c) * DF + n0;
    if (F32) {
      *(float2*)((float*)Bst + off) = make_float2(ab0, ab1);
      *(float2*)((float*)Cst + off) = make_float2(ac0, ac1);
    } else {
      *(uint32_t*)((uint16_t*)Bst + off) =
          (uint32_t)f2bf_u(ab0) | ((uint32_t)f2bf_u(ab1) << 16);
      *(uint32_t*)((uint16_t*)Cst + off) =
          (uint32_t)f2bf_u(ac0) | ((uint32_t)f2bf_u(ac1) << 16);
    }
  }
}

// --------------------------- chunk offsets (exclusive, fp32) ----------------
template<bool F32>
__global__ __launch_bounds__(256) void boff_kernel(
    const void* __restrict__ Bst, const void* __restrict__ Cst,
    float* __restrict__ Boff, float* __restrict__ Coff) {
  const int n = blockIdx.x * 256 + threadIdx.x;   // 4096 cols
  float ob = 0.f, oc = 0.f;
  for (int k = 0; k < NCHUNK; k++) {
    Boff[(size_t)k * DF + n] = ob;
    Coff[(size_t)k * DF + n] = oc;
    size_t off = (size_t)(k * CHUNK + CHUNK - 1) * DF + n;
    if (F32) { ob += ((const float*)Bst)[off]; oc += ((const float*)Cst)[off]; }
    else     { ob += bfu2f(((const uint16_t*)Bst)[off]);
               oc += bfu2f(((const uint16_t*)Cst)[off]); }
  }
  Boff[(size_t)NCHUNK * DF + n] = ob;   // = A_n (full total)
  Coff[(size_t)NCHUNK * DF + n] = oc;
}

// --------------------------- output assembly --------------------------------
template<bool F32>
__global__ __launch_bounds__(256) void assemble_kernel(
    const void* __restrict__ Bst, const void* __restrict__ Cst,
    const float* __restrict__ Boff, const float* __restrict__ Coff,
    const float* __restrict__ s1, const int* __restrict__ ci,
    const float* __restrict__ Sb, const float* __restrict__ Sc,
    float* __restrict__ out) {
  const int i = blockIdx.x;
  const float s1i = s1[i];
  const int c = ci[i];
  const float q1 = __expf(0.2f * s1i), q2 = __expf(s1i);
  const float l = q1 * (Sb[NB] - Sb[c]) + q2 * Sc[c];
  const float rl = 1.0f / l;
  const int row = c - 1;
  const int k = (c > 0) ? (row >> 8) : 0;     // CHUNK = 256
#pragma unroll
  for (int jj = 0; jj < 8; jj++) {
    const int n = (jj * 256 + threadIdx.x) * 2;
    float2 An = *(const float2*)(Boff + (size_t)NCHUNK * DF + n);
    float b0 = 0.f, b1 = 0.f, c0 = 0.f, c1 = 0.f;
    if (c > 0) {
      float2 Bo = *(const float2*)(Boff + (size_t)k * DF + n);
      float2 Co = *(const float2*)(Coff + (size_t)k * DF + n);
      size_t off = (size_t)row * DF + n;
      if (F32) {
        float2 bv = *(const float2*)((const float*)Bst + off);
        float2 cv = *(const float2*)((const float*)Cst + off);
        b0 = bv.x + Bo.x; b1 = bv.y + Bo.y;
        c0 = cv.x + Co.x; c1 = cv.y + Co.y;
      } else {
        uint32_t bv = *(const uint32_t*)((const uint16_t*)Bst + off);
        uint32_t cv = *(const uint32_t*)((const uint16_t*)Cst + off);
        b0 = bfu2f((uint16_t)bv) + Bo.x; b1 = bfu2f((uint16_t)(bv >> 16)) + Bo.y;
        c0 = bfu2f((uint16_t)cv) + Co.x; c1 = bfu2f((uint16_t)(cv >> 16)) + Co.y;
      }
    }
    float o0 = (q1 * (An.x - b0) + q2 * c0) * rl;
    float o1 = (q1 * (An.y - b1) + q2 * c1) * rl;
    *(float2*)(out + (size_t)i * DF + n) = make_float2(o0, o1);
  }
}

// ---------------------------------------------------------------------------
extern "C" void kernel_launch(void* const* d_in, const int* in_sizes, int n_in,
                              void* d_out, int out_size, void* d_ws, size_t ws_size,
                              hipStream_t stream) {
  const float* x = (const float*)d_in[0];   // [8192][4096] fp32
  const float* W = (const float*)d_in[1];   // [4096][4096] fp32
  const float* a = (const float*)d_in[2];   // [8192] fp32
  float* out = (float*)d_out;               // [8192][4096] fp32

  char* ws = (char*)d_ws;
  // layout:
  //   h (bf16, 67,108,864) | small (~2MB) | B | C   (xb/Wb overlap B/C region)
  uint16_t* h   = (uint16_t*)ws;
  char* sm      = ws + 67108864;
  float* s1       = (float*)(sm);
  float* s2       = (float*)(sm + 65536);
  float* s2sorted = (float*)(sm + 131072);
  int*   pi       = (int*)  (sm + 196608);
  int*   ci       = (int*)  (sm + 262144);
  float* Sb       = (float*)(sm + 327680);   // NB+1 floats
  float* Sc       = (float*)(sm + 393216);
  float* wbg      = (float*)(sm + 458752);
  float* wcg      = (float*)(sm + 524288);
  float* Boff     = (float*)(sm + 589824);   // (NCHUNK+1)*DF*4 = 540,672
  float* Coff     = (float*)(sm + 1179648);  // 540,672
  char*  big      = sm + 2097152;            // = ws + 69,206,016
  // B/C element type chosen by available workspace
  const size_t f32Need = 69206016ull + 2ull * 134217728ull;   // 337.6 MB
  const bool useF32 = (ws_size >= f32Need);
  void* Bst = (void*)big;
  void* Cst = (void*)(big + (useF32 ? 134217728 : 67108864));
  // GEMM1 staging overlaps B/C (dead after gemm):
  uint16_t* xb = (uint16_t*)big;                   // 64 MB
  uint16_t* Wb = (uint16_t*)(big + 67108864);      // 32 MB

  cvt_f32_to_bf16<<<1024, 256, 0, stream>>>(x, xb, (NB * DF) / 4);
  cvt_f32_to_bf16<<<1024, 256, 0, stream>>>(W, Wb, (DF * DF) / 4);

  // GEMM1: h[i][o] = sum_k x[i][k] W[o][k]   (M=8192, N=4096, K=4096)
  gemm_nt<true><<<dim3(DF / 128, NB / 128), 256, 0, stream>>>(
      xb, Wb, h, NB, DF, DF);

  s12_kernel<<<NB / 4, 256, 0, stream>>>(h, a, s1, s2);
  rank_kernel<<<NB / 256, 256, 0, stream>>>(s2, pi, s2sorted);
  count_kernel<<<NB / 256, 256, 0, stream>>>(s1, s2, ci);
  scan_kernel<<<1, 256, 0, stream>>>(s2sorted, Sb, Sc, wbg, wcg);

  if (useF32) {
    cumsum_kernel<true><<<dim3(DF / 512, NCHUNK), 256, 0, stream>>>(
        h, pi, wbg, wcg, Bst, Cst);
    boff_kernel<true><<<DF / 256, 256, 0, stream>>>(Bst, Cst, Boff, Coff);
    assemble_kernel<true><<<NB, 256, 0, stream>>>(
        Bst, Cst, Boff, Coff, s1, ci, Sb, Sc, out);
  } else {
    cumsum_kernel<false><<<dim3(DF / 512, NCHUNK), 256, 0, stream>>>(
        h, pi, wbg, wcg, Bst, Cst);
    boff_kernel<false><<<DF / 256, 256, 0, stream>>>(Bst, Cst, Boff, Coff);
    assemble_kernel<false><<<NB, 256, 0, stream>>>(
        Bst, Cst, Boff, Coff, s1, ci, Sb, Sc, out);
  }
}

// Round 3
// 955.400 us; speedup vs baseline: 1.2722x; 1.0604x over previous
//
#include <hip/hip_runtime.h>
#include <hip/hip_bf16.h>
#include <stdint.h>

// ---------------------------------------------------------------------------
// GraphAttentionLayer: out = softmax(lrelu(s1_i + s2_j)) @ h,  h = x @ W^T
// Round 3: rank-1 logit factorization (round 2) + bucketed direct emission:
// no B/C prefix matrices — one sweep kernel keeps fp32 running prefixes in
// registers and writes out rows at their boundary positions.
//   out_i = [q1_i*(A - B(c_i)) + q2_i*C(c_i)] / l_i
//   B/C = prefix sums (desc-sorted by s2) of exp(0.2 s2_j)h_j / exp(s2_j)h_j
// ---------------------------------------------------------------------------

typedef float  f32x4  __attribute__((ext_vector_type(4)));
typedef __bf16 bf16x8 __attribute__((ext_vector_type(8)));

#define AS1 __attribute__((address_space(1)))
#define AS3 __attribute__((address_space(3)))

constexpr int NB  = 8192;    // batch rows (i and j)
constexpr int DF  = 4096;    // feature dim
constexpr int CH  = 64;      // sweep chunk length
constexpr int NCH = NB / CH; // 128

__device__ __forceinline__ uint16_t f2bf_u(float f) {   // RNE fp32 -> bf16
  union { float f; uint32_t u; } x; x.f = f;
  return (uint16_t)((x.u + 0x7FFFu + ((x.u >> 16) & 1u)) >> 16);
}
__device__ __forceinline__ float bfu2f(uint16_t v) {
  union { uint32_t u; float f; } x; x.u = ((uint32_t)v) << 16;
  return x.f;
}

// --------------------------- fp32 -> bf16 convert ---------------------------
__global__ __launch_bounds__(256) void cvt_f32_to_bf16(
    const float* __restrict__ in, uint16_t* __restrict__ out, int n4) {
  int idx = blockIdx.x * 256 + threadIdx.x;
  int stride = gridDim.x * 256;
  for (int i = idx; i < n4; i += stride) {
    float4 v = ((const float4*)in)[i];
    ushort4 o;
    o.x = f2bf_u(v.x); o.y = f2bf_u(v.y); o.z = f2bf_u(v.z); o.w = f2bf_u(v.w);
    ((ushort4*)out)[i] = o;
  }
}

// --------------------------- NT bf16 GEMM (m97-style, unchanged) ------------
template<bool OUT_BF16>
__global__ __launch_bounds__(256, 2) void gemm_nt(
    const uint16_t* __restrict__ A, const uint16_t* __restrict__ B,
    void* __restrict__ C, int M, int N, int K) {
  __shared__ alignas(16) uint16_t As[128 * 32];
  __shared__ alignas(16) uint16_t Bs[128 * 32];

  const int tid  = threadIdx.x;
  const int wave = tid >> 6;
  const int lane = tid & 63;
  const int mBase = blockIdx.y * 128;
  const int nBase = blockIdx.x * 128;

  const int c0  = wave * 64 + lane;
  const int ar0 = c0 >> 2;
  const int ac0 = (c0 & 3) * 8;
  const uint16_t* Ag0 = A + (size_t)(mBase + ar0)      * K + ac0;
  const uint16_t* Ag1 = A + (size_t)(mBase + 64 + ar0) * K + ac0;
  const uint16_t* Bg0 = B + (size_t)(nBase + ar0)      * K + ac0;
  const uint16_t* Bg1 = B + (size_t)(nBase + 64 + ar0) * K + ac0;
  uint16_t* AsW0 = As + wave * 512;
  uint16_t* AsW1 = As + 2048 + wave * 512;
  uint16_t* BsW0 = Bs + wave * 512;
  uint16_t* BsW1 = Bs + 2048 + wave * 512;

  const int wm = (wave & 1) * 64;
  const int wn = (wave >> 1) * 64;
  const int lr = lane & 15;
  const int lk = (lane >> 4) * 8;

  f32x4 acc[4][4];
#pragma unroll
  for (int mi = 0; mi < 4; mi++)
#pragma unroll
    for (int ni = 0; ni < 4; ni++) acc[mi][ni] = (f32x4){0.f, 0.f, 0.f, 0.f};

  for (int k0 = 0; k0 < K; k0 += 32) {
    __builtin_amdgcn_global_load_lds((const AS1 void*)(Ag0 + k0), (AS3 void*)AsW0, 16, 0, 0);
    __builtin_amdgcn_global_load_lds((const AS1 void*)(Ag1 + k0), (AS3 void*)AsW1, 16, 0, 0);
    __builtin_amdgcn_global_load_lds((const AS1 void*)(Bg0 + k0), (AS3 void*)BsW0, 16, 0, 0);
    __builtin_amdgcn_global_load_lds((const AS1 void*)(Bg1 + k0), (AS3 void*)BsW1, 16, 0, 0);
    __syncthreads();

    bf16x8 af[4], bfr[4];
#pragma unroll
    for (int mi = 0; mi < 4; mi++)
      af[mi] = *(const bf16x8*)(As + (wm + mi * 16 + lr) * 32 + lk);
#pragma unroll
    for (int ni = 0; ni < 4; ni++)
      bfr[ni] = *(const bf16x8*)(Bs + (wn + ni * 16 + lr) * 32 + lk);
#pragma unroll
    for (int mi = 0; mi < 4; mi++)
#pragma unroll
      for (int ni = 0; ni < 4; ni++)
        acc[mi][ni] = __builtin_amdgcn_mfma_f32_16x16x32_bf16(
            af[mi], bfr[ni], acc[mi][ni], 0, 0, 0);
    __syncthreads();
  }

  const int row0 = mBase + wm + (lane >> 4) * 4;
  const int col0 = nBase + wn + lr;
#pragma unroll
  for (int mi = 0; mi < 4; mi++) {
#pragma unroll
    for (int r = 0; r < 4; r++) {
      const int row = row0 + mi * 16 + r;
#pragma unroll
      for (int ni = 0; ni < 4; ni++) {
        const int col = col0 + ni * 16;
        float v = acc[mi][ni][r];
        if (OUT_BF16)
          ((uint16_t*)C)[(size_t)row * N + col] = f2bf_u(v);
        else
          ((float*)C)[(size_t)row * N + col] = v;
      }
    }
  }
}

// --------------------------- s1/s2: h @ a1, h @ a2 --------------------------
__global__ __launch_bounds__(256) void s12_kernel(
    const uint16_t* __restrict__ h, const float* __restrict__ a,
    float* __restrict__ s1, float* __restrict__ s2) {
  const int wave = threadIdx.x >> 6, lane = threadIdx.x & 63;
  const int row = blockIdx.x * 4 + wave;
  const uint32_t* hr = (const uint32_t*)(h + (size_t)row * DF);
  float d1 = 0.f, d2 = 0.f;
#pragma unroll 4
  for (int it = 0; it < DF / 128; it++) {
    int u = it * 64 + lane;
    uint32_t hv = hr[u];
    float lo = bfu2f((uint16_t)hv), hi = bfu2f((uint16_t)(hv >> 16));
    int k = 2 * u;
    d1 += a[k] * lo + a[k + 1] * hi;
    d2 += a[DF + k] * lo + a[DF + k + 1] * hi;
  }
  for (int off = 32; off > 0; off >>= 1) {
    d1 += __shfl_down(d1, off, 64);
    d2 += __shfl_down(d2, off, 64);
  }
  if (lane == 0) { s1[row] = d1; s2[row] = d2; }
}

// --------------------------- rank sort of s2 (descending) -------------------
__global__ __launch_bounds__(256) void rank_kernel(
    const float* __restrict__ s2, int* __restrict__ pi,
    float* __restrict__ s2sorted) {
  __shared__ float ld[NB];
  for (int idx = threadIdx.x; idx < NB; idx += 256) ld[idx] = s2[idx];
  __syncthreads();
  const int j = blockIdx.x * 256 + threadIdx.x;
  const float v = ld[j];
  int cnt = 0;
  for (int q = 0; q < NB / 4; q++) {
    float4 u = ((const float4*)ld)[q];
    int jj = q * 4;
    cnt += (u.x > v) || (u.x == v && (jj + 0) < j);
    cnt += (u.y > v) || (u.y == v && (jj + 1) < j);
    cnt += (u.z > v) || (u.z == v && (jj + 2) < j);
    cnt += (u.w > v) || (u.w == v && (jj + 3) < j);
  }
  pi[cnt] = j;
  s2sorted[cnt] = v;
}

// --------------------------- c_i = #{j : s2_j > -s1_i} ----------------------
__global__ __launch_bounds__(256) void count_kernel(
    const float* __restrict__ s1, const float* __restrict__ s2,
    int* __restrict__ ci) {
  __shared__ float ld[NB];
  for (int idx = threadIdx.x; idx < NB; idx += 256) ld[idx] = s2[idx];
  __syncthreads();
  const int i = blockIdx.x * 256 + threadIdx.x;
  const float thr = -s1[i];
  int cnt = 0;
  for (int q = 0; q < NB / 4; q++) {
    float4 u = ((const float4*)ld)[q];
    cnt += (u.x > thr) + (u.y > thr) + (u.z > thr) + (u.w > thr);
  }
  ci[i] = cnt;
}

// --------------------------- scalar weights + prefix sums -------------------
__global__ __launch_bounds__(256) void scan_kernel(
    const float* __restrict__ s2sorted, float* __restrict__ Sb,
    float* __restrict__ Sc, float* __restrict__ wbg, float* __restrict__ wcg) {
  __shared__ float pb[256], pc[256];
  const int t = threadIdx.x;
  float sb = 0.f, sc = 0.f;
  for (int c = t * 32; c < t * 32 + 32; c++) {
    float s = s2sorted[c];
    float wb = __expf(0.2f * s), wc = __expf(s);
    wbg[c] = wb; wcg[c] = wc;
    sb += wb; sc += wc;
  }
  pb[t] = sb; pc[t] = sc;
  __syncthreads();
  if (t == 0) {
    float rb = 0.f, rc = 0.f;
    for (int q = 0; q < 256; q++) {
      float tb = pb[q], tc = pc[q];
      pb[q] = rb; pc[q] = rc;
      rb += tb; rc += tc;
    }
    Sb[0] = 0.f; Sc[0] = 0.f;
    Sb[NB] = rb; Sc[NB] = rc;
  }
  __syncthreads();
  float rb = pb[t], rc = pc[t];
  for (int c = t * 32; c < t * 32 + 32; c++) {
    rb += wbg[c]; rc += wcg[c];
    if (c + 1 < NB) { Sb[c + 1] = rb; Sc[c + 1] = rc; }
  }
}

// --------------------------- bucket machinery -------------------------------
__global__ __launch_bounds__(256) void zero_hist(int* __restrict__ hist) {
  int t = blockIdx.x * 256 + threadIdx.x;
  if (t <= NB) hist[t] = 0;
}

// per-i scalars f1,f2 and histogram of boundary buckets (bucket = c_i)
__global__ __launch_bounds__(256) void finalize_kernel(
    const float* __restrict__ s1, const int* __restrict__ ci,
    const float* __restrict__ Sb, const float* __restrict__ Sc,
    float* __restrict__ f1, float* __restrict__ f2, int* __restrict__ hist) {
  const int i = blockIdx.x * 256 + threadIdx.x;
  const float s1i = s1[i];
  const int c = ci[i];
  const float q1 = __expf(0.2f * s1i), q2 = __expf(s1i);
  const float l = q1 * (Sb[NB] - Sb[c]) + q2 * Sc[c];
  f1[i] = q1 / l;
  f2[i] = q2 / l;
  atomicAdd(&hist[c], 1);
}

// exclusive scan of hist[0..NB] -> istart[0..NB+1]; cursor = copy
__global__ __launch_bounds__(256) void bucket_scan(
    const int* __restrict__ hist, int* __restrict__ istart,
    int* __restrict__ cursor) {
  __shared__ int ps[256];
  const int t = threadIdx.x;
  const int lo = t * 33;
  const int hi = min(lo + 33, NB + 1);
  int s = 0;
  for (int b = lo; b < hi; b++) s += hist[b];
  ps[t] = s;
  __syncthreads();
  if (t == 0) {
    int r = 0;
    for (int q = 0; q < 256; q++) { int v = ps[q]; ps[q] = r; r += v; }
  }
  __syncthreads();
  int r = ps[t];
  for (int b = lo; b < hi; b++) { istart[b] = r; cursor[b] = r; r += hist[b]; }
  if (t == 255) istart[NB + 1] = r;
}

__global__ __launch_bounds__(256) void scatter_kernel(
    const int* __restrict__ ci, int* __restrict__ cursor,
    int* __restrict__ ilist) {
  const int i = blockIdx.x * 256 + threadIdx.x;
  const int b = ci[i];
  const int pos = atomicAdd(&cursor[b], 1);
  ilist[pos] = i;
}

// --------------------------- pass1: chunk totals ----------------------------
__global__ __launch_bounds__(256) void pass1_kernel(
    const uint16_t* __restrict__ h, const int* __restrict__ pi,
    const float* __restrict__ wbg, const float* __restrict__ wcg,
    float* __restrict__ Bct, float* __restrict__ Cct) {
  __shared__ int   pj[CH];
  __shared__ float wb[CH], wc[CH];
  const int t  = threadIdx.x;
  const int cb = blockIdx.x;
  const int k  = blockIdx.y;
  if (t < CH) {
    int g = k * CH + t;
    pj[t] = pi[g]; wb[t] = wbg[g]; wc[t] = wcg[g];
  }
  __syncthreads();
  const int n0 = cb * 512 + t * 2;
  float b0 = 0.f, b1 = 0.f, c0 = 0.f, c1 = 0.f;
#pragma unroll 4
  for (int c = 0; c < CH; c++) {
    uint32_t hv = *(const uint32_t*)(h + (size_t)pj[c] * DF + n0);
    float h0 = bfu2f((uint16_t)hv), h1 = bfu2f((uint16_t)(hv >> 16));
    b0 += wb[c] * h0; b1 += wb[c] * h1;
    c0 += wc[c] * h0; c1 += wc[c] * h1;
  }
  *(float2*)(Bct + (size_t)k * DF + n0) = make_float2(b0, b1);
  *(float2*)(Cct + (size_t)k * DF + n0) = make_float2(c0, c1);
}

// --------------------------- chunk offset scan (per column) -----------------
__global__ __launch_bounds__(256) void boff_kernel(
    const float* __restrict__ Bct, const float* __restrict__ Cct,
    float* __restrict__ Boff, float* __restrict__ Coff) {
  const int n = blockIdx.x * 256 + threadIdx.x;
  float ob = 0.f, oc = 0.f;
  for (int k = 0; k < NCH; k++) {
    Boff[(size_t)k * DF + n] = ob;
    Coff[(size_t)k * DF + n] = oc;
    ob += Bct[(size_t)k * DF + n];
    oc += Cct[(size_t)k * DF + n];
  }
  Boff[(size_t)NCH * DF + n] = ob;   // = A_n
  Coff[(size_t)NCH * DF + n] = oc;
}

// --------------------------- pass2: sweep + direct emission -----------------
__global__ __launch_bounds__(256) void pass2_kernel(
    const uint16_t* __restrict__ h, const int* __restrict__ pi,
    const float* __restrict__ wbg, const float* __restrict__ wcg,
    const float* __restrict__ Boff, const float* __restrict__ Coff,
    const int* __restrict__ istart, const int* __restrict__ ilist,
    const float* __restrict__ f1, const float* __restrict__ f2,
    float* __restrict__ out) {
  __shared__ int   pj[CH];
  __shared__ float wb[CH], wc[CH];
  __shared__ int   se[CH + 2];
  const int t  = threadIdx.x;
  const int cb = blockIdx.x;
  const int k  = blockIdx.y;
  if (t < CH) {
    int g = k * CH + t;
    pj[t] = pi[g]; wb[t] = wbg[g]; wc[t] = wcg[g];
  }
  if (t < CH + 2) se[t] = istart[k * CH + t];
  __syncthreads();
  const int n0 = cb * 512 + t * 2;
  const float2 An = *(const float2*)(Boff + (size_t)NCH * DF + n0);
  const float2 Bo = *(const float2*)(Boff + (size_t)k * DF + n0);
  const float2 Co = *(const float2*)(Coff + (size_t)k * DF + n0);
  float b0 = Bo.x, b1 = Bo.y, c0 = Co.x, c1 = Co.y;

  if (k == 0) {   // bucket 0: boundary before any j (c_i == 0)
    for (int idx = se[0]; idx < se[1]; idx++) {
      const int i = ilist[idx];
      const float fa = f1[i];
      *(float2*)(out + (size_t)i * DF + n0) = make_float2(fa * An.x, fa * An.y);
    }
  }
  for (int c = 0; c < CH; c++) {
    uint32_t hv = *(const uint32_t*)(h + (size_t)pj[c] * DF + n0);
    float h0 = bfu2f((uint16_t)hv), h1 = bfu2f((uint16_t)(hv >> 16));
    b0 += wb[c] * h0; b1 += wb[c] * h1;
    c0 += wc[c] * h0; c1 += wc[c] * h1;
    const int e0 = se[c + 1], e1 = se[c + 2];
    for (int idx = e0; idx < e1; idx++) {
      const int i = ilist[idx];
      const float fa = f1[i], fb = f2[i];
      float o0 = fa * (An.x - b0) + fb * c0;
      float o1 = fa * (An.y - b1) + fb * c1;
      *(float2*)(out + (size_t)i * DF + n0) = make_float2(o0, o1);
    }
  }
}

// ---------------------------------------------------------------------------
extern "C" void kernel_launch(void* const* d_in, const int* in_sizes, int n_in,
                              void* d_out, int out_size, void* d_ws, size_t ws_size,
                              hipStream_t stream) {
  const float* x = (const float*)d_in[0];   // [8192][4096] fp32
  const float* W = (const float*)d_in[1];   // [4096][4096] fp32
  const float* a = (const float*)d_in[2];   // [8192] fp32
  float* out = (float*)d_out;               // [8192][4096] fp32

  char* ws = (char*)d_ws;
  uint16_t* h = (uint16_t*)ws;                 // 64 MB
  char* sm = ws + 67108864;
  float* s1       = (float*)(sm);
  float* s2       = (float*)(sm + 65536);
  float* s2sorted = (float*)(sm + 131072);
  int*   pi       = (int*)  (sm + 196608);
  int*   ci       = (int*)  (sm + 262144);
  float* Sb       = (float*)(sm + 327680);     // NB+1 floats
  float* Sc       = (float*)(sm + 393216);
  float* wbg      = (float*)(sm + 458752);
  float* wcg      = (float*)(sm + 524288);
  float* f1       = (float*)(sm + 589824);
  float* f2       = (float*)(sm + 655360);
  int*   hist     = (int*)  (sm + 720896);     // NB+1 ints
  int*   istart   = (int*)  (sm + 786432);     // NB+2 ints
  int*   cursor   = (int*)  (sm + 851968);     // NB+1 ints
  int*   ilist    = (int*)  (sm + 917504);     // NB ints
  float* Bct      = (float*)(sm + 1048576);    // NCH*DF*4 = 2 MB
  float* Cct      = (float*)(sm + 3145728);    // 2 MB
  float* Boff     = (float*)(sm + 5242880);    // (NCH+1)*DF*4 ~ 2.02 MB
  float* Coff     = (float*)(sm + 7602176);    // ~2.02 MB (ends sm+9.96MB)
  char* base2 = ws + 67108864 + 10485760;      // staging (dead after gemm)
  uint16_t* xb = (uint16_t*)base2;             // 64 MB
  uint16_t* Wb = (uint16_t*)(base2 + 67108864);// 32 MB  (total ws ~169 MB)

  cvt_f32_to_bf16<<<1024, 256, 0, stream>>>(x, xb, (NB * DF) / 4);
  cvt_f32_to_bf16<<<1024, 256, 0, stream>>>(W, Wb, (DF * DF) / 4);

  // GEMM1: h[i][o] = sum_k x[i][k] W[o][k]   (M=8192, N=4096, K=4096)
  gemm_nt<true><<<dim3(DF / 128, NB / 128), 256, 0, stream>>>(
      xb, Wb, h, NB, DF, DF);

  zero_hist<<<33, 256, 0, stream>>>(hist);
  s12_kernel<<<NB / 4, 256, 0, stream>>>(h, a, s1, s2);
  rank_kernel<<<NB / 256, 256, 0, stream>>>(s2, pi, s2sorted);
  count_kernel<<<NB / 256, 256, 0, stream>>>(s1, s2, ci);
  scan_kernel<<<1, 256, 0, stream>>>(s2sorted, Sb, Sc, wbg, wcg);
  finalize_kernel<<<NB / 256, 256, 0, stream>>>(s1, ci, Sb, Sc, f1, f2, hist);
  bucket_scan<<<1, 256, 0, stream>>>(hist, istart, cursor);
  scatter_kernel<<<NB / 256, 256, 0, stream>>>(ci, cursor, ilist);

  pass1_kernel<<<dim3(DF / 512, NCH), 256, 0, stream>>>(h, pi, wbg, wcg, Bct, Cct);
  boff_kernel<<<DF / 256, 256, 0, stream>>>(Bct, Cct, Boff, Coff);
  pass2_kernel<<<dim3(DF / 512, NCH), 256, 0, stream>>>(
      h, pi, wbg, wcg, Boff, Coff, istart, ilist, f1, f2, out);
}